// Round 5
// baseline (294.372 us; speedup 1.0000x reference)
//
#include <hip/hip_runtime.h>
#include <math.h>

#define N_NODES 50000
#define N_EDGES 600000
#define H 128
#define BN_EPS 1e-5f
#define NSCAN_BLOCKS ((N_NODES + 255) / 256)   // 196

// ---------------- K0: zero counters + stats ----------------
__global__ void k_init(int* __restrict__ cnt, float* __restrict__ stats) {
    int i = blockIdx.x * blockDim.x + threadIdx.x;
    int stride = gridDim.x * blockDim.x;
    for (int j = i; j < N_NODES; j += stride) cnt[j] = 0;
    if (i < 256) stats[i] = 0.0f;
}

// ---------------- K1: in-degree histogram ----------------
__global__ void k_hist(const int* __restrict__ dst, int* __restrict__ cnt) {
    int i = blockIdx.x * blockDim.x + threadIdx.x;
    if (i < N_EDGES) atomicAdd(cnt + dst[i], 1);
}

// ---------------- K2a: per-block inclusive scan (256 elems/block) ----------------
__global__ void k_scan1(const int* __restrict__ cnt, int* __restrict__ incl,
                        int* __restrict__ bsum) {
    __shared__ int sm[256];
    int t = threadIdx.x;
    int i = blockIdx.x * 256 + t;
    sm[t] = (i < N_NODES) ? cnt[i] : 0;
    __syncthreads();
    for (int off = 1; off < 256; off <<= 1) {
        int add = (t >= off) ? sm[t - off] : 0;
        __syncthreads();
        sm[t] += add;
        __syncthreads();
    }
    if (i < N_NODES) incl[i] = sm[t];
    if (t == 255) bsum[blockIdx.x] = sm[255];
}

// ---------------- K2b: PARALLEL block-sum scan + offsets ----------------
__global__ void k_scan2(const int* __restrict__ incl, const int* __restrict__ cnt,
                        const int* __restrict__ bsum, int* __restrict__ row_off,
                        int* __restrict__ cursor) {
    __shared__ int sm[256];
    int t = threadIdx.x;
    sm[t] = (t < NSCAN_BLOCKS) ? bsum[t] : 0;
    __syncthreads();
    for (int off = 1; off < 256; off <<= 1) {
        int add = (t >= off) ? sm[t - off] : 0;
        __syncthreads();
        sm[t] += add;
        __syncthreads();
    }
    int boff = (blockIdx.x == 0) ? 0 : sm[blockIdx.x - 1];
    int i = blockIdx.x * 256 + t;
    if (i < N_NODES) {
        int e = incl[i] + boff - cnt[i];  // exclusive global offset
        row_off[i] = e;
        cursor[i] = e;
    }
}

// ---------------- K3: scatter src ids into dst-sorted (CSR) order ----------------
__global__ void k_scatter(const int* __restrict__ src, const int* __restrict__ dst,
                          int* __restrict__ cursor, int* __restrict__ srcs_sorted) {
    int i = blockIdx.x * blockDim.x + threadIdx.x;
    if (i < N_EDGES) {
        int pos = atomicAdd(cursor + dst[i], 1);
        srcs_sorted[pos] = src[i];
    }
}

#define F4SCALE(a, s) { (a).x *= (s); (a).y *= (s); (a).z *= (s); (a).w *= (s); }
#define F4FMA(a, e, v) { (a).x += (e)*(v).x; (a).y += (e)*(v).y; (a).z += (e)*(v).z; (a).w += (e)*(v).w; }
#define F4SHFLADD(a, msk) { (a).x += __shfl_xor((a).x, msk, 64); (a).y += __shfl_xor((a).y, msk, 64); \
                            (a).z += __shfl_xor((a).z, msk, 64); (a).w += __shfl_xor((a).w, msk, 64); }

// ---------------- K4: fused score + online softmax + aggregation ----------------
// one wave per dst node; 8 groups x 8 lanes, 8 edges in flight, lane owns 16 feats.
// Online softmax required: self-loop edges score ~|e|^2 ~128, exp overflows fp32.
__global__ __launch_bounds__(256) void k_fused(const float* __restrict__ emb,
                                               const int* __restrict__ row_off,
                                               const int* __restrict__ row_end,
                                               const int* __restrict__ srcs,
                                               float* __restrict__ neigh) {
    int wid = (blockIdx.x * blockDim.x + threadIdx.x) >> 6;
    int lane = threadIdx.x & 63;
    if (wid >= N_NODES) return;
    int g = lane >> 3;   // edge slot within chunk
    int l = lane & 7;    // feature slice

    int base = row_off[wid];
    int deg = row_end[wid] - base;

    const float4* rd = (const float4*)(emb + (size_t)wid * H) + l * 4;
    float4 b0 = rd[0], b1 = rd[1], b2 = rd[2], b3 = rd[3];

    float m = -INFINITY, ssum = 0.0f;
    float4 acc0 = {0,0,0,0}, acc1 = {0,0,0,0}, acc2 = {0,0,0,0}, acc3 = {0,0,0,0};

    for (int cb = 0; cb < deg; cb += 8) {
        int e = cb + g;
        bool valid = e < deg;
        int s = srcs[base + (valid ? e : 0)];
        const float4* rs = (const float4*)(emb + (size_t)s * H) + l * 4;
        float4 a0 = rs[0], a1 = rs[1], a2 = rs[2], a3 = rs[3];

        float v = a0.x*b0.x + a0.y*b0.y + a0.z*b0.z + a0.w*b0.w
                + a1.x*b1.x + a1.y*b1.y + a1.z*b1.z + a1.w*b1.w
                + a2.x*b2.x + a2.y*b2.y + a2.z*b2.z + a2.w*b2.w
                + a3.x*b3.x + a3.y*b3.y + a3.z*b3.z + a3.w*b3.w;
        v += __shfl_xor(v, 1, 64);
        v += __shfl_xor(v, 2, 64);
        v += __shfl_xor(v, 4, 64);
        if (!valid) v = -INFINITY;

        float cmax = v;
        cmax = fmaxf(cmax, __shfl_xor(cmax, 8, 64));
        cmax = fmaxf(cmax, __shfl_xor(cmax, 16, 64));
        cmax = fmaxf(cmax, __shfl_xor(cmax, 32, 64));
        float mnew = fmaxf(m, cmax);
        float scale = __expf(m - mnew);
        ssum *= scale;
        F4SCALE(acc0, scale); F4SCALE(acc1, scale);
        F4SCALE(acc2, scale); F4SCALE(acc3, scale);
        m = mnew;

        float ev = __expf(v - m);
        ssum += ev;
        F4FMA(acc0, ev, a0); F4FMA(acc1, ev, a1);
        F4FMA(acc2, ev, a2); F4FMA(acc3, ev, a3);
    }

    ssum += __shfl_xor(ssum, 8, 64);
    ssum += __shfl_xor(ssum, 16, 64);
    ssum += __shfl_xor(ssum, 32, 64);
    F4SHFLADD(acc0, 8);  F4SHFLADD(acc1, 8);  F4SHFLADD(acc2, 8);  F4SHFLADD(acc3, 8);
    F4SHFLADD(acc0, 16); F4SHFLADD(acc1, 16); F4SHFLADD(acc2, 16); F4SHFLADD(acc3, 16);
    F4SHFLADD(acc0, 32); F4SHFLADD(acc1, 32); F4SHFLADD(acc2, 32); F4SHFLADD(acc3, 32);

    float inv = (deg > 0) ? 1.0f / ssum : 0.0f;
    if (g == 0) {
        float4* po = (float4*)(neigh + (size_t)wid * H) + l * 4;
        F4SCALE(acc0, inv); F4SCALE(acc1, inv); F4SCALE(acc2, inv); F4SCALE(acc3, inv);
        po[0] = acc0; po[1] = acc1; po[2] = acc2; po[3] = acc3;
    }
}

// ---------------- K5: matmul h = neigh @ W -> d_out, fused BN column stats ----------------
// NO LDS operand staging: R rows via same-address broadcast dwordx4 (L1),
// W via coalesced dwordx4 (L2-resident, 64 KB). No barriers in the k-loop;
// occupancy-limited only by VGPRs. Writes h into OUT (not in-place) so no
// read/write ordering hazard exists. LDS only for the stats reduction (8 KB).
#define MM_ROWS 32
__global__ __launch_bounds__(256) void k_matmul(const float* __restrict__ neigh,
                                                const float* __restrict__ W,
                                                float* __restrict__ hout,
                                                float* __restrict__ stats) {
    __shared__ float Sl[8 * 128];   // 4 KB
    __shared__ float Ql[8 * 128];   // 4 KB
    int t = threadIdx.x;
    int n0 = blockIdx.x * MM_ROWS;
    int cg = t & 31, rg = t >> 5;
    int j0 = cg * 4, r0 = rg * 4;

    // clamped row pointers: invalid rows read row 0 (finite), masked at epilogue
    const float* pr[4];
    bool valid[4];
#pragma unroll
    for (int i = 0; i < 4; ++i) {
        int n = n0 + r0 + i;
        valid[i] = (n < N_NODES);
        pr[i] = neigh + (size_t)(valid[i] ? n : 0) * H;
    }

    float acc[4][4] = {};
    for (int k0 = 0; k0 < H; k0 += 4) {
        float rv[4][4];
        float wv[4][4];
#pragma unroll
        for (int i = 0; i < 4; ++i) *(float4*)&rv[i][0] = *(const float4*)(pr[i] + k0);
#pragma unroll
        for (int kk = 0; kk < 4; ++kk) *(float4*)&wv[kk][0] = *(const float4*)(W + (size_t)(k0 + kk) * H + j0);
#pragma unroll
        for (int kk = 0; kk < 4; ++kk)
#pragma unroll
            for (int i = 0; i < 4; ++i) {
                float rk = rv[i][kk];
                acc[i][0] += rk * wv[kk][0];
                acc[i][1] += rk * wv[kk][1];
                acc[i][2] += rk * wv[kk][2];
                acc[i][3] += rk * wv[kk][3];
            }
    }

    // store h rows
#pragma unroll
    for (int i = 0; i < 4; ++i) {
        if (valid[i]) {
            float4 o = make_float4(acc[i][0], acc[i][1], acc[i][2], acc[i][3]);
            *(float4*)(hout + (size_t)(n0 + r0 + i) * H + j0) = o;
        }
    }

    // fused BN column stats (masked rows excluded)
#pragma unroll
    for (int c = 0; c < 4; ++c) {
        float s = 0.0f, q = 0.0f;
#pragma unroll
        for (int i = 0; i < 4; ++i) {
            if (valid[i]) { s += acc[i][c]; q += acc[i][c] * acc[i][c]; }
        }
        Sl[rg * 128 + j0 + c] = s;
        Ql[rg * 128 + j0 + c] = q;
    }
    __syncthreads();
    if (t < 128) {
        float s = 0.0f;
#pragma unroll
        for (int r = 0; r < 8; ++r) s += Sl[r * 128 + t];
        atomicAdd(stats + t, s);
    } else {
        int j = t - 128;
        float q = 0.0f;
#pragma unroll
        for (int r = 0; r < 8; ++r) q += Ql[r * 128 + j];
        atomicAdd(stats + 128 + j, q);
    }
}

// ---------------- K6: finalize BN scale/shift ----------------
__global__ void k_finalize(const float* __restrict__ stats, const float* __restrict__ gamma,
                           const float* __restrict__ beta, float* __restrict__ ss) {
    int j = threadIdx.x;
    float mean = stats[j] * (1.0f / N_NODES);
    float var = stats[128 + j] * (1.0f / N_NODES) - mean * mean;
    var = fmaxf(var, 0.0f);
    float sc = gamma[j] * rsqrtf(var + BN_EPS);
    ss[j] = sc;
    ss[128 + j] = beta[j] - mean * sc;
}

// ---------------- K7: apply BN + tanh (in-place on d_out) ----------------
__global__ void k_apply(float* __restrict__ h, const float* __restrict__ ss) {
    int stride = gridDim.x * blockDim.x;
    for (int i = blockIdx.x * blockDim.x + threadIdx.x; i < N_NODES * H; i += stride) {
        int j = i & 127;
        h[i] = tanhf(h[i] * ss[j] + ss[128 + j]);
    }
}

extern "C" void kernel_launch(void* const* d_in, const int* in_sizes, int n_in,
                              void* d_out, int out_size, void* d_ws, size_t ws_size,
                              hipStream_t stream) {
    const float* emb   = (const float*)d_in[0];
    const float* W     = (const float*)d_in[1];
    const float* gamma = (const float*)d_in[2];
    const float* beta  = (const float*)d_in[3];
    const int*   src   = (const int*)d_in[4];
    const int*   dst   = (const int*)d_in[5];
    float* out = (float*)d_out;

    int* wsi = (int*)d_ws;
    int* cnt         = wsi;                       // N
    int* incl        = cnt + N_NODES;             // N
    int* bsum        = incl + N_NODES;            // 256 (196 used)
    int* row_off     = bsum + 256;                // N
    int* cursor      = row_off + N_NODES;         // N
    int* srcs_sorted = cursor + N_NODES;          // E
    float* neigh     = (float*)(srcs_sorted + N_EDGES);   // N*H
    float* stats     = neigh + (size_t)N_NODES * H;       // 256
    float* ss        = stats + 256;                       // 256

    k_init<<<NSCAN_BLOCKS, 256, 0, stream>>>(cnt, stats);
    k_hist<<<(N_EDGES + 255) / 256, 256, 0, stream>>>(dst, cnt);
    k_scan1<<<NSCAN_BLOCKS, 256, 0, stream>>>(cnt, incl, bsum);
    k_scan2<<<NSCAN_BLOCKS, 256, 0, stream>>>(incl, cnt, bsum, row_off, cursor);
    k_scatter<<<(N_EDGES + 255) / 256, 256, 0, stream>>>(src, dst, cursor, srcs_sorted);
    k_fused<<<(N_NODES * 64 + 255) / 256, 256, 0, stream>>>(emb, row_off, cursor, srcs_sorted, neigh);
    k_matmul<<<(N_NODES + MM_ROWS - 1) / MM_ROWS, 256, 0, stream>>>(neigh, W, out, stats);
    k_finalize<<<1, 128, 0, stream>>>(stats, gamma, beta, ss);
    k_apply<<<4096, 256, 0, stream>>>(out, ss);
}

// Round 6
// 264.201 us; speedup vs baseline: 1.1142x; 1.1142x over previous
//
#include <hip/hip_runtime.h>
#include <math.h>

#define N_NODES 50000
#define N_EDGES 600000
#define H 128
#define BN_EPS 1e-5f
#define NSCAN_BLOCKS ((N_NODES + 255) / 256)   // 196

// ---------------- K0: zero counters + stats ----------------
__global__ void k_init(int* __restrict__ cnt, float* __restrict__ stats) {
    int i = blockIdx.x * blockDim.x + threadIdx.x;
    int stride = gridDim.x * blockDim.x;
    for (int j = i; j < N_NODES; j += stride) cnt[j] = 0;
    if (i < 256) stats[i] = 0.0f;
}

// ---------------- K1: in-degree histogram ----------------
__global__ void k_hist(const int* __restrict__ dst, int* __restrict__ cnt) {
    int i = blockIdx.x * blockDim.x + threadIdx.x;
    if (i < N_EDGES) atomicAdd(cnt + dst[i], 1);
}

// ---------------- K2a: per-block inclusive scan (256 elems/block) ----------------
__global__ void k_scan1(const int* __restrict__ cnt, int* __restrict__ incl,
                        int* __restrict__ bsum) {
    __shared__ int sm[256];
    int t = threadIdx.x;
    int i = blockIdx.x * 256 + t;
    sm[t] = (i < N_NODES) ? cnt[i] : 0;
    __syncthreads();
    for (int off = 1; off < 256; off <<= 1) {
        int add = (t >= off) ? sm[t - off] : 0;
        __syncthreads();
        sm[t] += add;
        __syncthreads();
    }
    if (i < N_NODES) incl[i] = sm[t];
    if (t == 255) bsum[blockIdx.x] = sm[255];
}

// ---------------- K2b: PARALLEL block-sum scan + offsets ----------------
__global__ void k_scan2(const int* __restrict__ incl, const int* __restrict__ cnt,
                        const int* __restrict__ bsum, int* __restrict__ row_off,
                        int* __restrict__ cursor) {
    __shared__ int sm[256];
    int t = threadIdx.x;
    sm[t] = (t < NSCAN_BLOCKS) ? bsum[t] : 0;
    __syncthreads();
    for (int off = 1; off < 256; off <<= 1) {
        int add = (t >= off) ? sm[t - off] : 0;
        __syncthreads();
        sm[t] += add;
        __syncthreads();
    }
    int boff = (blockIdx.x == 0) ? 0 : sm[blockIdx.x - 1];
    int i = blockIdx.x * 256 + t;
    if (i < N_NODES) {
        int e = incl[i] + boff - cnt[i];  // exclusive global offset
        row_off[i] = e;
        cursor[i] = e;
    }
}

// ---------------- K3: scatter src ids into dst-sorted (CSR) order ----------------
__global__ void k_scatter(const int* __restrict__ src, const int* __restrict__ dst,
                          int* __restrict__ cursor, int* __restrict__ srcs_sorted) {
    int i = blockIdx.x * blockDim.x + threadIdx.x;
    if (i < N_EDGES) {
        int pos = atomicAdd(cursor + dst[i], 1);
        srcs_sorted[pos] = src[i];
    }
}

#define F4SCALE(a, s) { (a).x *= (s); (a).y *= (s); (a).z *= (s); (a).w *= (s); }
#define F4FMA(a, e, v) { (a).x += (e)*(v).x; (a).y += (e)*(v).y; (a).z += (e)*(v).z; (a).w += (e)*(v).w; }
#define F4SHFLADD(a, msk) { (a).x += __shfl_xor((a).x, msk, 64); (a).y += __shfl_xor((a).y, msk, 64); \
                            (a).z += __shfl_xor((a).z, msk, 64); (a).w += __shfl_xor((a).w, msk, 64); }

// ---------------- K4: fused score + online softmax + aggregation ----------------
// one wave per dst node; 8 groups x 8 lanes, 8 edges in flight, lane owns 16 feats.
// Online softmax required: self-loop edges score ~|e|^2 ~128, exp overflows fp32.
__global__ __launch_bounds__(256) void k_fused(const float* __restrict__ emb,
                                               const int* __restrict__ row_off,
                                               const int* __restrict__ row_end,
                                               const int* __restrict__ srcs,
                                               float* __restrict__ neigh) {
    int wid = (blockIdx.x * blockDim.x + threadIdx.x) >> 6;
    int lane = threadIdx.x & 63;
    if (wid >= N_NODES) return;
    int g = lane >> 3;   // edge slot within chunk
    int l = lane & 7;    // feature slice

    int base = row_off[wid];
    int deg = row_end[wid] - base;

    const float4* rd = (const float4*)(emb + (size_t)wid * H) + l * 4;
    float4 b0 = rd[0], b1 = rd[1], b2 = rd[2], b3 = rd[3];

    float m = -INFINITY, ssum = 0.0f;
    float4 acc0 = {0,0,0,0}, acc1 = {0,0,0,0}, acc2 = {0,0,0,0}, acc3 = {0,0,0,0};

    for (int cb = 0; cb < deg; cb += 8) {
        int e = cb + g;
        bool valid = e < deg;
        int s = srcs[base + (valid ? e : 0)];
        const float4* rs = (const float4*)(emb + (size_t)s * H) + l * 4;
        float4 a0 = rs[0], a1 = rs[1], a2 = rs[2], a3 = rs[3];

        float v = a0.x*b0.x + a0.y*b0.y + a0.z*b0.z + a0.w*b0.w
                + a1.x*b1.x + a1.y*b1.y + a1.z*b1.z + a1.w*b1.w
                + a2.x*b2.x + a2.y*b2.y + a2.z*b2.z + a2.w*b2.w
                + a3.x*b3.x + a3.y*b3.y + a3.z*b3.z + a3.w*b3.w;
        v += __shfl_xor(v, 1, 64);
        v += __shfl_xor(v, 2, 64);
        v += __shfl_xor(v, 4, 64);
        if (!valid) v = -INFINITY;

        float cmax = v;
        cmax = fmaxf(cmax, __shfl_xor(cmax, 8, 64));
        cmax = fmaxf(cmax, __shfl_xor(cmax, 16, 64));
        cmax = fmaxf(cmax, __shfl_xor(cmax, 32, 64));
        float mnew = fmaxf(m, cmax);
        float scale = __expf(m - mnew);
        ssum *= scale;
        F4SCALE(acc0, scale); F4SCALE(acc1, scale);
        F4SCALE(acc2, scale); F4SCALE(acc3, scale);
        m = mnew;

        float ev = __expf(v - m);
        ssum += ev;
        F4FMA(acc0, ev, a0); F4FMA(acc1, ev, a1);
        F4FMA(acc2, ev, a2); F4FMA(acc3, ev, a3);
    }

    ssum += __shfl_xor(ssum, 8, 64);
    ssum += __shfl_xor(ssum, 16, 64);
    ssum += __shfl_xor(ssum, 32, 64);
    F4SHFLADD(acc0, 8);  F4SHFLADD(acc1, 8);  F4SHFLADD(acc2, 8);  F4SHFLADD(acc3, 8);
    F4SHFLADD(acc0, 16); F4SHFLADD(acc1, 16); F4SHFLADD(acc2, 16); F4SHFLADD(acc3, 16);
    F4SHFLADD(acc0, 32); F4SHFLADD(acc1, 32); F4SHFLADD(acc2, 32); F4SHFLADD(acc3, 32);

    float inv = (deg > 0) ? 1.0f / ssum : 0.0f;
    if (g == 0) {
        float4* po = (float4*)(neigh + (size_t)wid * H) + l * 4;
        F4SCALE(acc0, inv); F4SCALE(acc1, inv); F4SCALE(acc2, inv); F4SCALE(acc3, inv);
        po[0] = acc0; po[1] = acc1; po[2] = acc2; po[3] = acc3;
    }
}

// ---------------- K5: matmul h = neigh @ W -> d_out, fused BN column stats ----------------
// FULL W staged in LDS once (64 KB, unpadded: full-row b128 reads already hit the
// 4-access structural minimum, no conflict penalty). ONE barrier total; the k-loop
// is barrier-free so loads pipeline freely. R rows via same-address broadcast
// float4 (1 L1 transaction per 32 lanes, streamed once). 8 rows x 4 cols per
// thread: 128 FMA per 12 mem instrs per 4-k step.
#define MM_ROWS 64
__global__ __launch_bounds__(256) void k_matmul(const float* __restrict__ neigh,
                                                const float* __restrict__ W,
                                                float* __restrict__ hout,
                                                float* __restrict__ stats) {
    __shared__ float Wl[H * H];     // 64 KB
    __shared__ float Sl[8 * 128];   // 4 KB
    __shared__ float Ql[8 * 128];   // 4 KB
    int t = threadIdx.x;
    int n0 = blockIdx.x * MM_ROWS;
    int cg = t & 31, rg = t >> 5;
    int j0 = cg * 4;
    int r0 = n0 + rg * 8;

    // stage all of W (coalesced float4)
    for (int idx = t; idx < H * 32; idx += 256) {
        int k = idx >> 5, c4 = idx & 31;
        *(float4*)&Wl[k * H + c4 * 4] = ((const float4*)(W + (size_t)k * H))[c4];
    }

    // clamped row pointers: invalid rows read row 0 (finite), masked at epilogue
    const float* pr[8];
    bool valid[8];
#pragma unroll
    for (int i = 0; i < 8; ++i) {
        int n = r0 + i;
        valid[i] = (n < N_NODES);
        pr[i] = neigh + (size_t)(valid[i] ? n : 0) * H;
    }

    __syncthreads();   // the only barrier before the epilogue

    float acc[8][4] = {};
    for (int k0 = 0; k0 < H; k0 += 4) {
        float4 rv[8];
#pragma unroll
        for (int i = 0; i < 8; ++i) rv[i] = *(const float4*)(pr[i] + k0);
        float4 wv[4];
#pragma unroll
        for (int kk = 0; kk < 4; ++kk) wv[kk] = *(const float4*)&Wl[(k0 + kk) * H + j0];
#pragma unroll
        for (int kk = 0; kk < 4; ++kk) {
#pragma unroll
            for (int i = 0; i < 8; ++i) {
                float rk = ((const float*)&rv[i])[kk];
                acc[i][0] += rk * wv[kk].x;
                acc[i][1] += rk * wv[kk].y;
                acc[i][2] += rk * wv[kk].z;
                acc[i][3] += rk * wv[kk].w;
            }
        }
    }

    // store h rows (coalesced float4 across cg)
#pragma unroll
    for (int i = 0; i < 8; ++i) {
        if (valid[i]) {
            float4 o = make_float4(acc[i][0], acc[i][1], acc[i][2], acc[i][3]);
            *(float4*)(hout + (size_t)(r0 + i) * H + j0) = o;
        }
    }

    // fused BN column stats (masked rows excluded): 8-row partials -> LDS -> atomics
#pragma unroll
    for (int c = 0; c < 4; ++c) {
        float s = 0.0f, q = 0.0f;
#pragma unroll
        for (int i = 0; i < 8; ++i) {
            if (valid[i]) { s += acc[i][c]; q += acc[i][c] * acc[i][c]; }
        }
        Sl[rg * 128 + j0 + c] = s;
        Ql[rg * 128 + j0 + c] = q;
    }
    __syncthreads();
    if (t < 128) {
        float s = 0.0f;
#pragma unroll
        for (int r = 0; r < 8; ++r) s += Sl[r * 128 + t];
        atomicAdd(stats + t, s);
    } else {
        int j = t - 128;
        float q = 0.0f;
#pragma unroll
        for (int r = 0; r < 8; ++r) q += Ql[r * 128 + j];
        atomicAdd(stats + 128 + j, q);
    }
}

// ---------------- K6: finalize BN scale/shift ----------------
__global__ void k_finalize(const float* __restrict__ stats, const float* __restrict__ gamma,
                           const float* __restrict__ beta, float* __restrict__ ss) {
    int j = threadIdx.x;
    float mean = stats[j] * (1.0f / N_NODES);
    float var = stats[128 + j] * (1.0f / N_NODES) - mean * mean;
    var = fmaxf(var, 0.0f);
    float sc = gamma[j] * rsqrtf(var + BN_EPS);
    ss[j] = sc;
    ss[128 + j] = beta[j] - mean * sc;
}

// ---------------- K7: apply BN + tanh (in-place on d_out) ----------------
__global__ void k_apply(float* __restrict__ h, const float* __restrict__ ss) {
    int stride = gridDim.x * blockDim.x;
    for (int i = blockIdx.x * blockDim.x + threadIdx.x; i < N_NODES * H; i += stride) {
        int j = i & 127;
        h[i] = tanhf(h[i] * ss[j] + ss[128 + j]);
    }
}

extern "C" void kernel_launch(void* const* d_in, const int* in_sizes, int n_in,
                              void* d_out, int out_size, void* d_ws, size_t ws_size,
                              hipStream_t stream) {
    const float* emb   = (const float*)d_in[0];
    const float* W     = (const float*)d_in[1];
    const float* gamma = (const float*)d_in[2];
    const float* beta  = (const float*)d_in[3];
    const int*   src   = (const int*)d_in[4];
    const int*   dst   = (const int*)d_in[5];
    float* out = (float*)d_out;

    int* wsi = (int*)d_ws;
    int* cnt         = wsi;                       // N
    int* incl        = cnt + N_NODES;             // N
    int* bsum        = incl + N_NODES;            // 256 (196 used)
    int* row_off     = bsum + 256;                // N
    int* cursor      = row_off + N_NODES;         // N
    int* srcs_sorted = cursor + N_NODES;          // E
    float* neigh     = (float*)(srcs_sorted + N_EDGES);   // N*H
    float* stats     = neigh + (size_t)N_NODES * H;       // 256
    float* ss        = stats + 256;                       // 256

    k_init<<<NSCAN_BLOCKS, 256, 0, stream>>>(cnt, stats);
    k_hist<<<(N_EDGES + 255) / 256, 256, 0, stream>>>(dst, cnt);
    k_scan1<<<NSCAN_BLOCKS, 256, 0, stream>>>(cnt, incl, bsum);
    k_scan2<<<NSCAN_BLOCKS, 256, 0, stream>>>(incl, cnt, bsum, row_off, cursor);
    k_scatter<<<(N_EDGES + 255) / 256, 256, 0, stream>>>(src, dst, cursor, srcs_sorted);
    k_fused<<<(N_NODES * 64 + 255) / 256, 256, 0, stream>>>(emb, row_off, cursor, srcs_sorted, neigh);
    k_matmul<<<(N_NODES + MM_ROWS - 1) / MM_ROWS, 256, 0, stream>>>(neigh, W, out, stats);
    k_finalize<<<1, 128, 0, stream>>>(stats, gamma, beta, ss);
    k_apply<<<4096, 256, 0, stream>>>(out, ss);
}

// Round 7
// 250.209 us; speedup vs baseline: 1.1765x; 1.0559x over previous
//
#include <hip/hip_runtime.h>
#include <math.h>

#define N_NODES 50000
#define N_EDGES 600000
#define H 128
#define BN_EPS 1e-5f
#define NSCAN_BLOCKS ((N_NODES + 255) / 256)   // 196

// ---------------- K0: zero counters + stats ----------------
__global__ void k_init(int* __restrict__ cnt, float* __restrict__ stats) {
    int i = blockIdx.x * blockDim.x + threadIdx.x;
    int stride = gridDim.x * blockDim.x;
    for (int j = i; j < N_NODES; j += stride) cnt[j] = 0;
    if (i < 256) stats[i] = 0.0f;
}

// ---------------- K1: in-degree histogram ----------------
__global__ void k_hist(const int* __restrict__ dst, int* __restrict__ cnt) {
    int i = blockIdx.x * blockDim.x + threadIdx.x;
    if (i < N_EDGES) atomicAdd(cnt + dst[i], 1);
}

// ---------------- K2a: per-block inclusive scan (256 elems/block) ----------------
__global__ void k_scan1(const int* __restrict__ cnt, int* __restrict__ incl,
                        int* __restrict__ bsum) {
    __shared__ int sm[256];
    int t = threadIdx.x;
    int i = blockIdx.x * 256 + t;
    sm[t] = (i < N_NODES) ? cnt[i] : 0;
    __syncthreads();
    for (int off = 1; off < 256; off <<= 1) {
        int add = (t >= off) ? sm[t - off] : 0;
        __syncthreads();
        sm[t] += add;
        __syncthreads();
    }
    if (i < N_NODES) incl[i] = sm[t];
    if (t == 255) bsum[blockIdx.x] = sm[255];
}

// ---------------- K2b: PARALLEL block-sum scan + offsets ----------------
__global__ void k_scan2(const int* __restrict__ incl, const int* __restrict__ cnt,
                        const int* __restrict__ bsum, int* __restrict__ row_off,
                        int* __restrict__ cursor) {
    __shared__ int sm[256];
    int t = threadIdx.x;
    sm[t] = (t < NSCAN_BLOCKS) ? bsum[t] : 0;
    __syncthreads();
    for (int off = 1; off < 256; off <<= 1) {
        int add = (t >= off) ? sm[t - off] : 0;
        __syncthreads();
        sm[t] += add;
        __syncthreads();
    }
    int boff = (blockIdx.x == 0) ? 0 : sm[blockIdx.x - 1];
    int i = blockIdx.x * 256 + t;
    if (i < N_NODES) {
        int e = incl[i] + boff - cnt[i];  // exclusive global offset
        row_off[i] = e;
        cursor[i] = e;
    }
}

// ---------------- K3: scatter src ids into dst-sorted (CSR) order ----------------
__global__ void k_scatter(const int* __restrict__ src, const int* __restrict__ dst,
                          int* __restrict__ cursor, int* __restrict__ srcs_sorted) {
    int i = blockIdx.x * blockDim.x + threadIdx.x;
    if (i < N_EDGES) {
        int pos = atomicAdd(cursor + dst[i], 1);
        srcs_sorted[pos] = src[i];
    }
}

#define F4SCALE(a, s) { (a).x *= (s); (a).y *= (s); (a).z *= (s); (a).w *= (s); }
#define F4FMA(a, e, v) { (a).x += (e)*(v).x; (a).y += (e)*(v).y; (a).z += (e)*(v).z; (a).w += (e)*(v).w; }
#define F4SHFLADD(a, msk) { (a).x += __shfl_xor((a).x, msk, 64); (a).y += __shfl_xor((a).y, msk, 64); \
                            (a).z += __shfl_xor((a).z, msk, 64); (a).w += __shfl_xor((a).w, msk, 64); }

// ---------------- K4: fused score + online softmax + aggregation ----------------
// one wave per dst node; 8 groups x 8 lanes, 8 edges in flight, lane owns 16 feats.
// Online softmax required: self-loop edges score ~|e|^2 ~128, exp overflows fp32.
__global__ __launch_bounds__(256) void k_fused(const float* __restrict__ emb,
                                               const int* __restrict__ row_off,
                                               const int* __restrict__ row_end,
                                               const int* __restrict__ srcs,
                                               float* __restrict__ neigh) {
    int wid = (blockIdx.x * blockDim.x + threadIdx.x) >> 6;
    int lane = threadIdx.x & 63;
    if (wid >= N_NODES) return;
    int g = lane >> 3;   // edge slot within chunk
    int l = lane & 7;    // feature slice

    int base = row_off[wid];
    int deg = row_end[wid] - base;

    const float4* rd = (const float4*)(emb + (size_t)wid * H) + l * 4;
    float4 b0 = rd[0], b1 = rd[1], b2 = rd[2], b3 = rd[3];

    float m = -INFINITY, ssum = 0.0f;
    float4 acc0 = {0,0,0,0}, acc1 = {0,0,0,0}, acc2 = {0,0,0,0}, acc3 = {0,0,0,0};

    for (int cb = 0; cb < deg; cb += 8) {
        int e = cb + g;
        bool valid = e < deg;
        int s = srcs[base + (valid ? e : 0)];
        const float4* rs = (const float4*)(emb + (size_t)s * H) + l * 4;
        float4 a0 = rs[0], a1 = rs[1], a2 = rs[2], a3 = rs[3];

        float v = a0.x*b0.x + a0.y*b0.y + a0.z*b0.z + a0.w*b0.w
                + a1.x*b1.x + a1.y*b1.y + a1.z*b1.z + a1.w*b1.w
                + a2.x*b2.x + a2.y*b2.y + a2.z*b2.z + a2.w*b2.w
                + a3.x*b3.x + a3.y*b3.y + a3.z*b3.z + a3.w*b3.w;
        v += __shfl_xor(v, 1, 64);
        v += __shfl_xor(v, 2, 64);
        v += __shfl_xor(v, 4, 64);
        if (!valid) v = -INFINITY;

        float cmax = v;
        cmax = fmaxf(cmax, __shfl_xor(cmax, 8, 64));
        cmax = fmaxf(cmax, __shfl_xor(cmax, 16, 64));
        cmax = fmaxf(cmax, __shfl_xor(cmax, 32, 64));
        float mnew = fmaxf(m, cmax);
        float scale = __expf(m - mnew);
        ssum *= scale;
        F4SCALE(acc0, scale); F4SCALE(acc1, scale);
        F4SCALE(acc2, scale); F4SCALE(acc3, scale);
        m = mnew;

        float ev = __expf(v - m);
        ssum += ev;
        F4FMA(acc0, ev, a0); F4FMA(acc1, ev, a1);
        F4FMA(acc2, ev, a2); F4FMA(acc3, ev, a3);
    }

    ssum += __shfl_xor(ssum, 8, 64);
    ssum += __shfl_xor(ssum, 16, 64);
    ssum += __shfl_xor(ssum, 32, 64);
    F4SHFLADD(acc0, 8);  F4SHFLADD(acc1, 8);  F4SHFLADD(acc2, 8);  F4SHFLADD(acc3, 8);
    F4SHFLADD(acc0, 16); F4SHFLADD(acc1, 16); F4SHFLADD(acc2, 16); F4SHFLADD(acc3, 16);
    F4SHFLADD(acc0, 32); F4SHFLADD(acc1, 32); F4SHFLADD(acc2, 32); F4SHFLADD(acc3, 32);

    float inv = (deg > 0) ? 1.0f / ssum : 0.0f;
    if (g == 0) {
        float4* po = (float4*)(neigh + (size_t)wid * H) + l * 4;
        F4SCALE(acc0, inv); F4SCALE(acc1, inv); F4SCALE(acc2, inv); F4SCALE(acc3, inv);
        po[0] = acc0; po[1] = acc1; po[2] = acc2; po[3] = acc3;
    }
}

// ---------------- K5: matmul h = neigh @ W -> d_out, fused BN column stats ----------------
// Column-split tiles: block (br, bc) computes rows [br*128, +128) x cols [bc*64, +64),
// staging only W[:, bc*64 .. +64) = 32 KB in LDS -> 40 KB/block -> 4 blocks/CU
// (16 waves/CU; round 6's full-W 72 KB allowed only 2 -> 14% occupancy, latency-bound).
// k-loop is barrier-free: R rows via same-address broadcast float4 (L1), W via LDS.
#define MM_ROWS 128
#define MM_COLS 64
__global__ __launch_bounds__(256, 4) void k_matmul(const float* __restrict__ neigh,
                                                   const float* __restrict__ W,
                                                   float* __restrict__ hout,
                                                   float* __restrict__ stats) {
    __shared__ float Wl[H * MM_COLS];    // 32 KB
    __shared__ float Sl[16 * MM_COLS];   // 4 KB
    __shared__ float Ql[16 * MM_COLS];   // 4 KB
    int t = threadIdx.x;
    int bc = blockIdx.x & 1;
    int br = blockIdx.x >> 1;
    int c0 = bc * MM_COLS;
    int n0 = br * MM_ROWS;
    int cg = t & 15, rg = t >> 4;
    int j0 = cg * 4;            // column within [0,64)
    int r0 = n0 + rg * 8;

    // stage W[:, c0:c0+64] (coalesced float4)
    for (int idx = t; idx < H * 16; idx += 256) {
        int k = idx >> 4, c4 = idx & 15;
        *(float4*)&Wl[k * MM_COLS + c4 * 4] =
            *((const float4*)(W + (size_t)k * H + c0) + c4);
    }

    // clamped row pointers: invalid rows read row 0 (finite), masked at epilogue
    const float* pr[8];
    bool valid[8];
#pragma unroll
    for (int i = 0; i < 8; ++i) {
        int n = r0 + i;
        valid[i] = (n < N_NODES);
        pr[i] = neigh + (size_t)(valid[i] ? n : 0) * H;
    }

    __syncthreads();   // only barrier before epilogue

    float acc[8][4] = {};
    for (int k0 = 0; k0 < H; k0 += 4) {
        float4 rv[8];
#pragma unroll
        for (int i = 0; i < 8; ++i) rv[i] = *(const float4*)(pr[i] + k0);
        float4 wv[4];
#pragma unroll
        for (int kk = 0; kk < 4; ++kk) wv[kk] = *(const float4*)&Wl[(k0 + kk) * MM_COLS + j0];
#pragma unroll
        for (int kk = 0; kk < 4; ++kk) {
#pragma unroll
            for (int i = 0; i < 8; ++i) {
                float rk = ((const float*)&rv[i])[kk];
                acc[i][0] += rk * wv[kk].x;
                acc[i][1] += rk * wv[kk].y;
                acc[i][2] += rk * wv[kk].z;
                acc[i][3] += rk * wv[kk].w;
            }
        }
    }

    // store h tile
#pragma unroll
    for (int i = 0; i < 8; ++i) {
        if (valid[i]) {
            float4 o = make_float4(acc[i][0], acc[i][1], acc[i][2], acc[i][3]);
            *(float4*)(hout + (size_t)(r0 + i) * H + c0 + j0) = o;
        }
    }

    // fused BN column stats for this tile's 64 columns
#pragma unroll
    for (int c = 0; c < 4; ++c) {
        float s = 0.0f, q = 0.0f;
#pragma unroll
        for (int i = 0; i < 8; ++i) {
            if (valid[i]) { s += acc[i][c]; q += acc[i][c] * acc[i][c]; }
        }
        Sl[rg * MM_COLS + j0 + c] = s;
        Ql[rg * MM_COLS + j0 + c] = q;
    }
    __syncthreads();
    if (t < MM_COLS) {
        float s = 0.0f;
#pragma unroll
        for (int r = 0; r < 16; ++r) s += Sl[r * MM_COLS + t];
        atomicAdd(stats + c0 + t, s);
    } else if (t < 2 * MM_COLS) {
        int j = t - MM_COLS;
        float q = 0.0f;
#pragma unroll
        for (int r = 0; r < 16; ++r) q += Ql[r * MM_COLS + j];
        atomicAdd(stats + 128 + c0 + j, q);
    }
}

// fast tanh via v_exp: 1 - 2/(exp(2x)+1); saturates correctly at +/-inf
__device__ __forceinline__ float tanh_fast(float x) {
    float e = __expf(2.0f * x);
    return 1.0f - 2.0f / (e + 1.0f);
}

// ---------------- K6: finalize BN (in LDS) + apply + tanh, in-place on d_out ----------------
__global__ __launch_bounds__(256) void k_apply(float* __restrict__ h,
                                               const float* __restrict__ stats,
                                               const float* __restrict__ gamma,
                                               const float* __restrict__ beta) {
    __shared__ float sc[128], sh[128];
    int t = threadIdx.x;
    if (t < 128) {
        float mean = stats[t] * (1.0f / N_NODES);
        float var = stats[128 + t] * (1.0f / N_NODES) - mean * mean;
        var = fmaxf(var, 0.0f);
        float s = gamma[t] * rsqrtf(var + BN_EPS);
        sc[t] = s;
        sh[t] = beta[t] - mean * s;
    }
    __syncthreads();
    int i = blockIdx.x * 256 + t;                  // float4 index
    if (i < N_NODES * H / 4) {
        float4 v = ((const float4*)h)[i];
        int jb = (i & 31) * 4;
        v.x = tanh_fast(v.x * sc[jb]     + sh[jb]);
        v.y = tanh_fast(v.y * sc[jb + 1] + sh[jb + 1]);
        v.z = tanh_fast(v.z * sc[jb + 2] + sh[jb + 2]);
        v.w = tanh_fast(v.w * sc[jb + 3] + sh[jb + 3]);
        ((float4*)h)[i] = v;
    }
}

extern "C" void kernel_launch(void* const* d_in, const int* in_sizes, int n_in,
                              void* d_out, int out_size, void* d_ws, size_t ws_size,
                              hipStream_t stream) {
    const float* emb   = (const float*)d_in[0];
    const float* W     = (const float*)d_in[1];
    const float* gamma = (const float*)d_in[2];
    const float* beta  = (const float*)d_in[3];
    const int*   src   = (const int*)d_in[4];
    const int*   dst   = (const int*)d_in[5];
    float* out = (float*)d_out;

    int* wsi = (int*)d_ws;
    int* cnt         = wsi;                       // N
    int* incl        = cnt + N_NODES;             // N
    int* bsum        = incl + N_NODES;            // 256 (196 used)
    int* row_off     = bsum + 256;                // N
    int* cursor      = row_off + N_NODES;         // N
    int* srcs_sorted = cursor + N_NODES;          // E
    float* neigh     = (float*)(srcs_sorted + N_EDGES);   // N*H
    float* stats     = neigh + (size_t)N_NODES * H;       // 256

    k_init<<<NSCAN_BLOCKS, 256, 0, stream>>>(cnt, stats);
    k_hist<<<(N_EDGES + 255) / 256, 256, 0, stream>>>(dst, cnt);
    k_scan1<<<NSCAN_BLOCKS, 256, 0, stream>>>(cnt, incl, bsum);
    k_scan2<<<NSCAN_BLOCKS, 256, 0, stream>>>(incl, cnt, bsum, row_off, cursor);
    k_scatter<<<(N_EDGES + 255) / 256, 256, 0, stream>>>(src, dst, cursor, srcs_sorted);
    k_fused<<<(N_NODES * 64 + 255) / 256, 256, 0, stream>>>(emb, row_off, cursor, srcs_sorted, neigh);
    k_matmul<<<((N_NODES + MM_ROWS - 1) / MM_ROWS) * 2, 256, 0, stream>>>(neigh, W, out, stats);
    k_apply<<<(N_NODES * H / 4 + 255) / 256, 256, 0, stream>>>(out, stats, gamma, beta);
}